// Round 7
// baseline (83.455 us; speedup 1.0000x reference)
//
#include <hip/hip_runtime.h>
#include <hip/hip_bf16.h>
#include <math.h>

typedef short bf16x8 __attribute__((ext_vector_type(8)));
typedef float f32x4 __attribute__((ext_vector_type(4)));
typedef float f32x16 __attribute__((ext_vector_type(16)));
typedef unsigned short u16;

#define AS1(p) ((const __attribute__((address_space(1))) unsigned int*)(p))
#define AS3(p) ((__attribute__((address_space(3))) unsigned int*)(p))

#define WAITVM6 asm volatile("s_waitcnt vmcnt(6)" ::: "memory")
#define WAITVM0 asm volatile("s_waitcnt vmcnt(0)" ::: "memory")
#define BARRIER asm volatile("s_barrier" ::: "memory")

__device__ __forceinline__ u16 f2bf(float f) {
  union { float f; unsigned u; } v; v.f = f;
  unsigned r = v.u + 0x7fffu + ((v.u >> 16) & 1u);  // RNE
  return (u16)(r >> 16);
}

// pack 8 fp32 -> 8 bf16 by truncation (exact for 0.0/1.0 adj values)
__device__ __forceinline__ bf16x8 pack8_trunc(const f32x4& a, const f32x4& b) {
  union { f32x4 f; unsigned u[4]; } ua, ub; ua.f = a; ub.f = b;
  union { bf16x8 v; unsigned u[4]; } r;
  r.u[0] = (ua.u[0] >> 16) | (ua.u[1] & 0xFFFF0000u);
  r.u[1] = (ua.u[2] >> 16) | (ua.u[3] & 0xFFFF0000u);
  r.u[2] = (ub.u[0] >> 16) | (ub.u[1] & 0xFFFF0000u);
  r.u[3] = (ub.u[2] >> 16) | (ub.u[3] & 0xFFFF0000u);
  return r.v;
}

// ---------- Kernel 0: Wt[f][k] = bf16(W[k][f]) (256x256) ----------
__global__ void k_wt(const float* __restrict__ W, u16* __restrict__ Wt) {
  int idx = blockIdx.x * 256 + threadIdx.x;
#pragma unroll
  for (int q = 0; q < 4; ++q) {
    int i = idx + q * 16384;
    int f = i & 255, k = i >> 8;
    Wt[f * 256 + k] = f2bf(W[k * 256 + f]);
  }
}

// ---------- Kernel A: ht[b][f][j] = bf16( (x @ W)[b,j,f] ) ----------
// bid&7 = batch -> batch b's ht is written by XCD-b blocks, stays in its L2.
__global__ __launch_bounds__(512, 4) void k_xw(
    const float* __restrict__ x, const u16* __restrict__ Wt, u16* __restrict__ ht)
{
  __shared__ u16 Ab[2][32 * 64];
  __shared__ u16 Bb[2][256 * 64];

  const int tid = threadIdx.x;
  const int lane = tid & 63;
  const int wid = tid >> 6;
  const int wr = wid >> 2, wc = wid & 3;

  const int b  = blockIdx.x & 7;        // batch -> XCD-local ht writes
  const int jt = blockIdx.x >> 3;       // 0..63
  const int jloc = jt * 32;
  const float* xb = x + ((size_t)b * 2048 + jloc) * 256;
  u16* htb = ht + ((size_t)b << 19);

  const int ar = tid >> 4;
  const int ac = tid & 15;
  const int awb = ar * 128 + ((ac * 8) ^ ((ar & 7) << 4));

  f32x4 acc[4] = {};

  auto stage = [&](int t, int bufi) {
    const float4 v = *(const float4*)(xb + ar * 256 + t * 64 + ac * 4);
    short4 p;
    p.x = (short)f2bf(v.x); p.y = (short)f2bf(v.y);
    p.z = (short)f2bf(v.z); p.w = (short)f2bf(v.w);
    *(short4*)((char*)(&Ab[bufi][0]) + awb) = p;
#pragma unroll
    for (int q = 0; q < 4; ++q) {
      const int fbase = wid * 32 + q * 8;
      const int f = fbase + (lane >> 3);
      const char* src = (const char*)Wt + f * 512 + t * 128
                        + (((lane & 7) * 16) ^ ((f & 7) << 4));
      __builtin_amdgcn_global_load_lds(AS1(src),
          AS3((char*)(&Bb[bufi][0]) + fbase * 128), 16, 0, 0);
    }
  };

  auto compute = [&](int bufi) {
#pragma unroll
    for (int kk = 0; kk < 2; ++kk) {
      const int am = wr * 16 + (lane & 15);
      const bf16x8 a = *(const bf16x8*)((const char*)(&Ab[bufi][0])
          + am * 128 + ((kk * 64 + (lane >> 4) * 16) ^ ((am & 7) << 4)));
#pragma unroll
      for (int nf = 0; nf < 4; ++nf) {
        const int bn = wc * 64 + nf * 16 + (lane & 15);
        const bf16x8 bv = *(const bf16x8*)((const char*)(&Bb[bufi][0])
            + bn * 128 + ((kk * 64 + (lane >> 4) * 16) ^ ((bn & 7) << 4)));
        acc[nf] = __builtin_amdgcn_mfma_f32_16x16x32_bf16(a, bv, acc[nf], 0, 0, 0);
      }
    }
  };

  stage(0, 0);
  __syncthreads();
#pragma unroll 2
  for (int t = 0; t < 4; ++t) {
    const int cur = t & 1;
    if (t + 1 < 4) stage(t + 1, cur ^ 1);
    compute(cur);
    __syncthreads();
  }

  const int j0 = jloc + wr * 16 + ((lane >> 4) << 2);
#pragma unroll
  for (int nf = 0; nf < 4; ++nf) {
    const int f = wc * 64 + nf * 16 + (lane & 15);
    short4 p;
    p.x = (short)f2bf(acc[nf][0]);
    p.y = (short)f2bf(acc[nf][1]);
    p.z = (short)f2bf(acc[nf][2]);
    p.w = (short)f2bf(acc[nf][3]);
    *(short4*)(&htb[(size_t)f * 2048 + j0]) = p;
  }
}

// ---------- Kernel B: out = elu( (1/deg) * adj @ h ) ----------
// Round-6 structure. NEW (single variable): cache-policy control.
//  - adj gload_lds aux=0x2 (CPol.NT streaming, read-once) -> doesn't evict ht
//  - out stores nontemporal -> don't evict ht
// B-restream then hits XCD-local L2; external traffic = adj once from HBM.
__global__ __launch_bounds__(512, 1) void k_agg(
    const float* __restrict__ adj, const u16* __restrict__ ht, float* __restrict__ out)
{
  __shared__ float Abuf[3][64 * 64];   // 16KB x3: adj [64r][64k] fp32, slot^(row&15)
  __shared__ u16   Bbuf[3][256 * 64];  // 32KB x3: ht  [256f][64k] bf16, slot^(f&7)

  const int tid  = threadIdx.x;
  const int lane = tid & 63;
  const int wid  = tid >> 6;
  const int sm   = wid >> 2;          // 0..1: m-strip (32 rows)
  const int sn   = wid & 3;           // 0..3: f-strip (64 f)

  const int b  = blockIdx.x & 7;      // batch -> XCD-local ht in L2
  const int rt = blockIdx.x >> 3;     // 0..31

  const char* adjB = (const char*)(adj + ((size_t)b * 2048 + rt * 64) * 2048);
  const char* htB  = (const char*)(ht + ((size_t)b << 19));
  float* outb = out + ((size_t)b * 2048 + rt * 64) * 256;

  // 6 VMEM/wave per stage: 4 B-gload_lds (cached) + 2 A-gload_lds (NT)
  auto stage = [&](int t, int r) {
#pragma unroll
    for (int q = 0; q < 4; ++q) {     // B: f = q*64 + wid*8 + (lane>>3)
      const int f = q * 64 + wid * 8 + (lane >> 3);
      const int s = lane & 7;
      const char* src = htB + (size_t)f * 4096 + (size_t)t * 128 + ((s ^ (f & 7)) * 16);
      __builtin_amdgcn_global_load_lds(AS1(src),
          AS3((char*)(&Bbuf[r][0]) + q * 8192 + wid * 1024), 16, 0, 0);
    }
#pragma unroll
    for (int q = 0; q < 2; ++q) {     // A: row = q*32 + wid*4 + (lane>>4)
      const int row = q * 32 + wid * 4 + (lane >> 4);
      const int s = lane & 15;
      const char* src = adjB + (size_t)row * 8192 + (size_t)t * 256 + ((s ^ (row & 15)) * 16);
      __builtin_amdgcn_global_load_lds(AS1(src),
          AS3((char*)(&Abuf[r][0]) + q * 8192 + wid * 1024), 16, 0, 2);  // NT
    }
  };

  f32x16 acc[2] = {};                 // 2 nf x (32m x 32f)
  f32x16 dacc = {};                   // deg accumulator (ones-MFMA)
  bf16x8 vones;
#pragma unroll
  for (int i = 0; i < 8; ++i) vones[i] = (short)0x3F80;  // bf16 1.0

  const int lo = lane & 31;           // frag row/col
  const int hi = lane >> 5;           // k-half within K=16

  stage(0, 0);
  stage(1, 1);

  for (int t = 0; t < 32; ++t) {
    if (t < 31) { WAITVM6; } else { WAITVM0; }   // tile t landed; t+1 in flight
    BARRIER;
    const int r = t % 3;
    if (t < 30) stage(t + 2, (t + 2) % 3);       // ring slot freed at t-1
    const char* Ab = (const char*)(&Abuf[r][0]);
    const char* Bb = (const char*)(&Bbuf[r][0]);
    const int arow = sm * 32 + lo;
    const char* Arb = Ab + arow * 256;
#pragma unroll
    for (int ksl = 0; ksl < 4; ++ksl) {
      // A frag: k = ksl*16 + hi*8 .. +8 (fp32, swizzled slot^(row&15))
      const int s0 = ksl * 4 + hi * 2;
      const f32x4 a0 = *(const f32x4*)(Arb + (((s0 + 0) ^ (arow & 15)) * 16));
      const f32x4 a1 = *(const f32x4*)(Arb + (((s0 + 1) ^ (arow & 15)) * 16));
      const bf16x8 af = pack8_trunc(a0, a1);
      dacc = __builtin_amdgcn_mfma_f32_32x32x16_bf16(af, vones, dacc, 0, 0, 0);
#pragma unroll
      for (int nf = 0; nf < 2; ++nf) {
        const int f = sn * 64 + nf * 32 + lo;
        const bf16x8 bv = *(const bf16x8*)(Bb + f * 128
            + (((ksl * 2 + hi) ^ (f & 7)) * 16));
        acc[nf] = __builtin_amdgcn_mfma_f32_32x32x16_bf16(af, bv, acc[nf], 0, 0, 0);
      }
    }
  }

  // epilogue: C/D 32x32: col = lane&31, row = (reg&3)+8*(reg>>2)+4*hi.
  // NT stores: don't evict ht from L2.
#pragma unroll
  for (int reg = 0; reg < 16; ++reg) {
    const int rl = (reg & 3) + 8 * (reg >> 2) + 4 * hi;
    const float d = dacc[reg];
    const float sc = d > 0.f ? 1.f / d : (1.f / 2048.f);
    float* orow = outb + (size_t)(sm * 32 + rl) * 256 + sn * 64 + lo;
#pragma unroll
    for (int nf = 0; nf < 2; ++nf) {
      const float v = acc[nf][reg] * sc;
      __builtin_nontemporal_store(v > 0.f ? v : expm1f(v), orow + nf * 32);
    }
  }
}

extern "C" void kernel_launch(void* const* d_in, const int* in_sizes, int n_in,
                              void* d_out, int out_size, void* d_ws, size_t ws_size,
                              hipStream_t stream) {
  const float* x   = (const float*)d_in[0];
  const float* adj = (const float*)d_in[1];
  const float* W   = (const float*)d_in[2];
  // d_in[3] ('a') is mathematically dead: softmax rows are constant over the
  // active (adj>0) entries, so attention = 1/deg regardless of e.
  float* out = (float*)d_out;

  u16* Wt = (u16*)d_ws;                          // 256*256*2   = 128 KB
  u16* ht = (u16*)((char*)d_ws + (131072));      // 8*256*2048*2 = 8 MB

  k_wt<<<64, 256, 0, stream>>>(W, Wt);
  k_xw<<<512, 512, 0, stream>>>(x, Wt, ht);
  k_agg<<<256, 512, 0, stream>>>(adj, ht, out);
}

// Round 8
// 71.601 us; speedup vs baseline: 1.1656x; 1.1656x over previous
//
#include <hip/hip_runtime.h>
#include <hip/hip_bf16.h>
#include <math.h>

typedef short bf16x8 __attribute__((ext_vector_type(8)));
typedef float f32x4 __attribute__((ext_vector_type(4)));
typedef float f32x16 __attribute__((ext_vector_type(16)));
typedef unsigned short u16;
typedef unsigned long long u64;

#define AS1(p) ((const __attribute__((address_space(1))) unsigned int*)(p))
#define AS3(p) ((__attribute__((address_space(3))) unsigned int*)(p))

#define WAITVM2 asm volatile("s_waitcnt vmcnt(2)" ::: "memory")
#define WAITVM0 asm volatile("s_waitcnt vmcnt(0)" ::: "memory")
#define BARRIER asm volatile("s_barrier" ::: "memory")

__device__ __forceinline__ u16 f2bf(float f) {
  union { float f; unsigned u; } v; v.f = f;
  unsigned r = v.u + 0x7fffu + ((v.u >> 16) & 1u);  // RNE
  return (u16)(r >> 16);
}

// ---------- Kernel P: bit-pack adj + row degree ----------
// grid 4096 = 8 batches x 512 rowgroups (bid&7 = batch -> XCD-local bits/deg).
// 256 thr = 4 waves, 1 row/wave; lane l owns j = l*32..+32 (one u32 mask).
// u32 slots stored PRE-SWIZZLED (8B unit u -> u^(row&7)) so k_agg's LDS copy
// can stay linear (rule: swizzle source + read, never the gload_lds dest).
__global__ __launch_bounds__(256) void k_pack(
    const float* __restrict__ adj, unsigned* __restrict__ bits, float* __restrict__ deg)
{
  const int b   = blockIdx.x & 7;
  const int rg  = blockIdx.x >> 3;        // 0..511
  const int wid = threadIdx.x >> 6;
  const int l   = threadIdx.x & 63;
  const int row = rg * 4 + wid;           // 0..2047
  const float* src = adj + ((size_t)b * 2048 + row) * 2048 + l * 32;
  unsigned m = 0;
#pragma unroll
  for (int q = 0; q < 8; ++q) {
    const float4 v = *(const float4*)(src + q * 4);
    m |= (v.x > 0.f ? 1u : 0u) << (q * 4);
    m |= (v.y > 0.f ? 2u : 0u) << (q * 4);
    m |= (v.z > 0.f ? 4u : 0u) << (q * 4);
    m |= (v.w > 0.f ? 8u : 0u) << (q * 4);
  }
  int d = __popc(m);
#pragma unroll
  for (int s = 1; s < 64; s <<= 1) d += __shfl_xor(d, s);
  const int idx = ((((l >> 1) ^ (row & 7)) << 1) | (l & 1));   // swizzled u32 slot
  bits[((size_t)b * 2048 + row) * 64 + idx] = m;
  if (l == 0) deg[(size_t)b * 2048 + row] = (float)d;
}

// ---------- Kernel 0: Wt[f][k] = bf16(W[k][f]) (256x256) ----------
__global__ void k_wt(const float* __restrict__ W, u16* __restrict__ Wt) {
  int idx = blockIdx.x * 256 + threadIdx.x;
#pragma unroll
  for (int q = 0; q < 4; ++q) {
    int i = idx + q * 16384;
    int f = i & 255, k = i >> 8;
    Wt[f * 256 + k] = f2bf(W[k * 256 + f]);
  }
}

// ---------- Kernel A: ht[b][f][j] = bf16( (x @ W)[b,j,f] ) ----------
// bid&7 = batch -> batch b's ht written by XCD-b blocks, stays in its L2.
__global__ __launch_bounds__(512, 4) void k_xw(
    const float* __restrict__ x, const u16* __restrict__ Wt, u16* __restrict__ ht)
{
  __shared__ u16 Ab[2][32 * 64];
  __shared__ u16 Bb[2][256 * 64];

  const int tid = threadIdx.x;
  const int lane = tid & 63;
  const int wid = tid >> 6;
  const int wr = wid >> 2, wc = wid & 3;

  const int b  = blockIdx.x & 7;
  const int jt = blockIdx.x >> 3;
  const int jloc = jt * 32;
  const float* xb = x + ((size_t)b * 2048 + jloc) * 256;
  u16* htb = ht + ((size_t)b << 19);

  const int ar = tid >> 4;
  const int ac = tid & 15;
  const int awb = ar * 128 + ((ac * 8) ^ ((ar & 7) << 4));

  f32x4 acc[4] = {};

  auto stage = [&](int t, int bufi) {
    const float4 v = *(const float4*)(xb + ar * 256 + t * 64 + ac * 4);
    short4 p;
    p.x = (short)f2bf(v.x); p.y = (short)f2bf(v.y);
    p.z = (short)f2bf(v.z); p.w = (short)f2bf(v.w);
    *(short4*)((char*)(&Ab[bufi][0]) + awb) = p;
#pragma unroll
    for (int q = 0; q < 4; ++q) {
      const int fbase = wid * 32 + q * 8;
      const int f = fbase + (lane >> 3);
      const char* src = (const char*)Wt + f * 512 + t * 128
                        + (((lane & 7) * 16) ^ ((f & 7) << 4));
      __builtin_amdgcn_global_load_lds(AS1(src),
          AS3((char*)(&Bb[bufi][0]) + fbase * 128), 16, 0, 0);
    }
  };

  auto compute = [&](int bufi) {
#pragma unroll
    for (int kk = 0; kk < 2; ++kk) {
      const int am = wr * 16 + (lane & 15);
      const bf16x8 a = *(const bf16x8*)((const char*)(&Ab[bufi][0])
          + am * 128 + ((kk * 64 + (lane >> 4) * 16) ^ ((am & 7) << 4)));
#pragma unroll
      for (int nf = 0; nf < 4; ++nf) {
        const int bn = wc * 64 + nf * 16 + (lane & 15);
        const bf16x8 bv = *(const bf16x8*)((const char*)(&Bb[bufi][0])
            + bn * 128 + ((kk * 64 + (lane >> 4) * 16) ^ ((bn & 7) << 4)));
        acc[nf] = __builtin_amdgcn_mfma_f32_16x16x32_bf16(a, bv, acc[nf], 0, 0, 0);
      }
    }
  };

  stage(0, 0);
  __syncthreads();
#pragma unroll 2
  for (int t = 0; t < 4; ++t) {
    const int cur = t & 1;
    if (t + 1 < 4) stage(t + 1, cur ^ 1);
    compute(cur);
    __syncthreads();
  }

  const int j0 = jloc + wr * 16 + ((lane >> 4) << 2);
#pragma unroll
  for (int nf = 0; nf < 4; ++nf) {
    const int f = wc * 64 + nf * 16 + (lane & 15);
    short4 p;
    p.x = (short)f2bf(acc[nf][0]);
    p.y = (short)f2bf(acc[nf][1]);
    p.z = (short)f2bf(acc[nf][2]);
    p.w = (short)f2bf(acc[nf][3]);
    *(short4*)(&htb[(size_t)f * 2048 + j0]) = p;
  }
}

// ---------- Kernel B: out = elu( (1/deg) * adj @ h ) ----------
// grid 256 = 8 b x 16 rt x 2 nt; block tile 128m x 128n, BK=64; 8 waves
// (4 sm x 2 sn), wave = 32m x 64f, 32x32x16 MFMA.
// A = bitmask: whole block's 32 KB of row-bits loaded to LDS ONCE (prologue);
// in-loop staging is B only (2 gload_lds/thread from XCD-local L2).
// A-fragments expanded bits->bf16{0,1} in-register (exact). deg precomputed.
__global__ __launch_bounds__(512, 1) void k_agg(
    const unsigned* __restrict__ bits, const float* __restrict__ deg,
    const u16* __restrict__ ht, float* __restrict__ out)
{
  __shared__ unsigned bitsLds[128 * 64];   // 32 KB: [128 rows][256 B bits], pre-swizzled 8B units
  __shared__ u16 Bbuf[3][128 * 64];        // 16 KB x3: ht [128f][64k] bf16, slot^(f&7)

  const int tid  = threadIdx.x;
  const int lane = tid & 63;
  const int wid  = tid >> 6;
  const int sm   = wid >> 1;          // 0..3: 32-row strip
  const int sn   = wid & 1;           // 0..1: 64-f strip

  const int b  = blockIdx.x & 7;
  const int rt = (blockIdx.x >> 3) & 15;
  const int nt = blockIdx.x >> 7;     // 0 or 1
  const int row0 = rt * 128;

  const char* bsrc = (const char*)(bits + ((size_t)b * 2048 + row0) * 64);
  const char* htB  = (const char*)ht + ((size_t)b << 20) + (size_t)nt * 524288;
  const float* degB = deg + (size_t)b * 2048 + row0;
  float* outb = out + ((size_t)b * 2048 + row0) * 256 + nt * 128;

  // prologue: bits 32 KB -> LDS, linear (source already swizzled by k_pack)
#pragma unroll
  for (int q = 0; q < 4; ++q) {
    __builtin_amdgcn_global_load_lds(AS1(bsrc + q * 8192 + wid * 1024 + lane * 16),
        AS3((char*)bitsLds + q * 8192 + wid * 1024), 16, 0, 0);
  }

  // B stage: 2 gload_lds/thread per tile
  auto stage = [&](int t, int r) {
#pragma unroll
    for (int q = 0; q < 2; ++q) {
      const int f = q * 64 + wid * 8 + (lane >> 3);
      const int s = lane & 7;
      const char* src = htB + (size_t)f * 4096 + (size_t)t * 128 + ((s ^ (f & 7)) * 16);
      __builtin_amdgcn_global_load_lds(AS1(src),
          AS3((char*)(&Bbuf[r][0]) + q * 8192 + wid * 1024), 16, 0, 0);
    }
  };

  f32x16 acc[2] = {};
  const int lo = lane & 31;
  const int hi = lane >> 5;
  const int arow = sm * 32 + lo;

  stage(0, 0);
  stage(1, 1);

  for (int t = 0; t < 32; ++t) {
    if (t < 31) { WAITVM2; } else { WAITVM0; }   // tile t (+bits at t=0) landed
    BARRIER;
    const int r = t % 3;
    if (t < 30) stage(t + 2, (t + 2) % 3);       // ring slot freed at t-1
    // row bits for this K-tile: 8 bytes (64 k), swizzled 8B-unit read
    const u64 rowbits = *(const u64*)((const char*)bitsLds
        + arow * 256 + ((t ^ (arow & 7)) * 8));
    const char* Bb = (const char*)(&Bbuf[r][0]);
#pragma unroll
    for (int ksl = 0; ksl < 4; ++ksl) {
      const unsigned byte = (unsigned)(rowbits >> ((ksl * 2 + hi) * 8)) & 0xFFu;
      union { bf16x8 v; unsigned u[4]; } af;
#pragma unroll
      for (int w = 0; w < 4; ++w) {
        const unsigned l16 = ((byte >> (2 * w)) & 1u) * 0x3F80u;
        const unsigned h16 = ((byte >> (2 * w + 1)) & 1u) * 0x3F80u;
        af.u[w] = l16 | (h16 << 16);
      }
#pragma unroll
      for (int nf = 0; nf < 2; ++nf) {
        const int f = sn * 64 + nf * 32 + lo;
        const bf16x8 bv = *(const bf16x8*)(Bb + f * 128
            + (((ksl * 2 + hi) ^ (f & 7)) * 16));
        acc[nf] = __builtin_amdgcn_mfma_f32_32x32x16_bf16(af.v, bv, acc[nf], 0, 0, 0);
      }
    }
  }

  // epilogue: C/D 32x32: col = lane&31, row = (reg&3)+8*(reg>>2)+4*hi
#pragma unroll
  for (int reg = 0; reg < 16; ++reg) {
    const int rl = (reg & 3) + 8 * (reg >> 2) + 4 * hi;
    const float d = degB[sm * 32 + rl];
    const float sc = d > 0.f ? 1.f / d : (1.f / 2048.f);
    float* orow = outb + (size_t)(sm * 32 + rl) * 256 + sn * 64 + lo;
#pragma unroll
    for (int nf = 0; nf < 2; ++nf) {
      const float v = acc[nf][reg] * sc;
      orow[nf * 32] = v > 0.f ? v : expm1f(v);
    }
  }
}

extern "C" void kernel_launch(void* const* d_in, const int* in_sizes, int n_in,
                              void* d_out, int out_size, void* d_ws, size_t ws_size,
                              hipStream_t stream) {
  const float* x   = (const float*)d_in[0];
  const float* adj = (const float*)d_in[1];
  const float* W   = (const float*)d_in[2];
  // d_in[3] ('a') is mathematically dead: softmax rows are constant over the
  // active (adj>0) entries, so attention = 1/deg regardless of e.
  float* out = (float*)d_out;

  u16*      Wt   = (u16*)d_ws;                              // 128 KB
  u16*      ht   = (u16*)((char*)d_ws + 131072);            // 8 MB
  unsigned* bits = (unsigned*)((char*)d_ws + 8519680);      // 4 MB
  float*    degp = (float*)((char*)d_ws + 12713984);        // 64 KB

  // k_pack FIRST: its 134 MB adj stream must not evict ht from L2.
  k_pack<<<4096, 256, 0, stream>>>(adj, bits, degp);
  k_wt<<<64, 256, 0, stream>>>(W, Wt);
  k_xw<<<512, 512, 0, stream>>>(x, Wt, ht);
  k_agg<<<256, 512, 0, stream>>>(bits, degp, ht, out);
}